// Round 18
// baseline (269.937 us; speedup 1.0000x reference)
//
#include <hip/hip_runtime.h>

using f32x4  = __attribute__((ext_vector_type(4))) float;
using bf16x8 = __attribute__((ext_vector_type(8))) __bf16;
using u16x4  = __attribute__((ext_vector_type(4))) unsigned short;

#define BK 64
#define REG_HALF   8192      // ushorts: 128 rows x 64 cols
#define A_OFS      0
#define B_OFS      16384
#define BUF_STRIDE 32768     // one buffer = A(32KB)+B(32KB) = 64 KB

#define BARRIER() __builtin_amdgcn_s_barrier()
#define SGB()     __builtin_amdgcn_sched_barrier(0)
#define SGB_NOMFMA() __builtin_amdgcn_sched_barrier(0x3F7)

__device__ __forceinline__ unsigned short f32_to_bf16_bits(float f) {
    unsigned int u = __builtin_bit_cast(unsigned int, f);
    u = (u + 0x7fffu + ((u >> 16) & 1u)) >> 16;
    return (unsigned short)u;
}

__device__ __forceinline__ void gload_lds16(const void* g, void* l) {
    __builtin_amdgcn_global_load_lds(
        (const __attribute__((address_space(1))) unsigned int*)g,
        (__attribute__((address_space(3))) unsigned int*)l,
        16, 0, 0);
}

// ---------------------------------------------------------------------------
// Fused prep: fake-quant x (exact-f32 math, bf16 store) + W f32->bf16.
// ---------------------------------------------------------------------------
__global__ void prep_kernel(const float* __restrict__ x,
                            const float* __restrict__ W,
                            unsigned short* __restrict__ xq,
                            unsigned short* __restrict__ Wb,
                            int t4x, int t4w) {
    int idx = blockIdx.x * 256 + threadIdx.x;
    if (idx < t4x) {
        f32x4 v = *(const f32x4*)(x + (size_t)idx * 4);
        float am = fmaxf(fmaxf(fabsf(v[0]), fabsf(v[1])),
                         fmaxf(fabsf(v[2]), fabsf(v[3])));
        am = fmaxf(am, __shfl_xor(am, 1));
        am = fmaxf(am, __shfl_xor(am, 2));
        am = fmaxf(am, __shfl_xor(am, 4));
        am = fmaxf(am, __shfl_xor(am, 8));
        float delta = fmaxf(am / 127.0f, 1e-5f);
        u16x4 o;
#pragma unroll
        for (int i = 0; i < 4; ++i) {
            float q = rintf(v[i] / delta);           // round-half-even
            q = fminf(fmaxf(q, -127.0f), 127.0f);
            o[i] = f32_to_bf16_bits(q * delta);
        }
        *(u16x4*)(xq + (size_t)idx * 4) = o;
    } else {
        int j = idx - t4x;
        if (j < t4w) {
            f32x4 v = *(const f32x4*)(W + (size_t)j * 4);
            u16x4 o;
#pragma unroll
            for (int i = 0; i < 4; ++i) o[i] = f32_to_bf16_bits(v[i]);
            *(u16x4*)(Wb + (size_t)j * 4) = o;
        }
    }
}

// Fragment readers (region base pointer; T2-swizzled column) ---------------
__device__ __forceinline__ void read_af(bf16x8 (&dst)[4][2],
    const unsigned short* reg, int wm, int lr, int lk, int sx) {
#pragma unroll
    for (int m = 0; m < 4; ++m)
#pragma unroll
        for (int kk = 0; kk < 2; ++kk)
            dst[m][kk] = *(const bf16x8*)(reg
                + (wm * 64 + m * 16 + lr) * 64 + ((((kk << 2) + lk) ^ sx) << 3));
}

__device__ __forceinline__ void read_bf(bf16x8 (&dst)[2][2],
    const unsigned short* reg, int wn, int lr, int lk, int sx) {
#pragma unroll
    for (int n = 0; n < 2; ++n)
#pragma unroll
        for (int kk = 0; kk < 2; ++kk)
            dst[n][kk] = *(const bf16x8*)(reg
                + (wn * 32 + n * 16 + lr) * 64 + ((((kk << 2) + lk) ^ sx) << 3));
}

// Operand-SWAPPED quad: mfma(bf, af) -> D-fragment transposed:
// lane&15 = M-row, (lane>>4)*4+j = N-col. Numerically identical.
__device__ __forceinline__ void mfma_quad(f32x4 (&acc)[8][4], int mo, int no,
    const bf16x8 (&af)[4][2], const bf16x8 (&bf)[2][2]) {
#pragma unroll
    for (int m = 0; m < 4; ++m)
#pragma unroll
        for (int n = 0; n < 2; ++n)
#pragma unroll
            for (int kk = 0; kk < 2; ++kk)
                acc[mo + m][no + n] = __builtin_amdgcn_mfma_f32_16x16x32_bf16(
                    bf[n][kk], af[m][kk], acc[mo + m][no + n], 0, 0, 0);
}

// ---------------------------------------------------------------------------
// 256x256 bf16 GEMM (B^T), 2-phase/tile, NO cross-tile register rotation
// (round-9 spill lesson: rotation killed 2-phase; this reads bfA+bfB+afL
// together in P1, all consumed within the tile — peak ~84 live VGPR).
// P1: { read afL,bfA,bfB (16 b128) ; vmcnt(6) ; SGB ; BAR ;
//       stage A-h1(t+1)->nb ; SGB_NOMFMA ; setprio1 Q1,Q2 setprio0 ;
//       SGB_NOMFMA }
// P2: { read afH (8 b128) ; vmcnt(2) ; SGB ; BAR ;
//       stage A-h0,B-h0,B-h1(t+2)->cb ; SGB_NOMFMA ; setprio1 Q3,Q4
//       setprio0 ; SGB_NOMFMA }
// Stages are POST-barrier — that is what makes 2 barriers sufficient:
// WAR (stage after a barrier that follows the dying region's read delivery):
//   S(t.P1) nb.A-h1 over A-h1(t-1): read (t-1).P2, delivered < M((t-1).P2)
//     < BAR(t.P1) in every wave; stage issued after BAR(t.P1). OK
//   S(t.P2) cb.{A-h0,B-h0,B-h1} over tile t's: read t.P1, delivered <
//     M(t.P1) < BAR(t.P2); stage issued after BAR(t.P2). OK
// RAW (read after the barrier whose preceding vmcnt proved its region):
//   reads(t.P1) regions staged S(t-2).P2: proven by W((t-1).P2)=vmcnt(2)
//     before BAR((t-1).P2); reads issue after it. OK
//   reads(t.P2) region A-h1(t) staged S(t-1).P1: proven by W(t.P1)=vmcnt(6)
//     before BAR(t.P1). OK (SGB fences keep reads below their vmcnt; floats
//     down past SGB_NOMFMA are harmless — proof barrier already passed.)
// vmcnt ledger (loads: P1-stage=2, P2-stage=6; induction-verified):
//   at W(t.P1): outstanding {S(t-1.P1):2, S(t-1.P2):6}=8 -> vmcnt(6)
//     retires S(t-1.P1).
//   at W(t.P2): outstanding {S(t-1.P2):6, S(t.P1):2}=8 -> vmcnt(2)
//     retires S(t-1.P2).
// Prologue: c1={A-h0,B-h0,B-h1}(0):6, c2=A-h1(0):2, c3={...}(1):6;
//   vmcnt(8) retires c1; t0.P1's vmcnt(6) retires c2; t0.P2's vmcnt(2)
//   retires c3 — exact steady state. Tail: sources clamped to NT-1
//   (dead-region writes, ledger uniform); vmcnt(0) drain after loop.
// Stage->wait distance = 1 full tile (~4000 cyc) >> 900-cyc HBM miss.
// ---------------------------------------------------------------------------
__global__ __launch_bounds__(512, 2) void gemm_kernel(
    const unsigned short* __restrict__ A,   // [M][K] bf16 bits (quantized x)
    const unsigned short* __restrict__ B,   // [N][K] bf16 bits (W)
    const float* __restrict__ bias,         // [N]
    float* __restrict__ out,                // [M][N] f32
    int M, int N, int K)
{
    __shared__ unsigned short lds[2 * BUF_STRIDE];   // 128 KiB

    const int tid  = threadIdx.x;
    const int lane = tid & 63;
    const int wv   = tid >> 6;
    const int wm   = wv >> 2;        // 0..1  (128 rows each)
    const int wn   = wv & 3;         // 0..3  (64 cols each)
    const int lr   = lane & 15;
    const int lk   = lane >> 4;      // 0..3
    const int sx   = lr & 7;

    const int nbn = N / 256;
    const int nwg = gridDim.x;
    const int cpx = nwg >> 3;        // bijective XCD swizzle (nwg % 8 == 0)
    const int swz = (blockIdx.x & 7) * cpx + (blockIdx.x >> 3);
    const int bm0 = (swz / nbn) * 256;
    const int bn0 = (swz % nbn) * 256;

    const unsigned short* Ag = A + (size_t)bm0 * K;
    const unsigned short* Bg = B + (size_t)bn0 * K;
    const int NT = K / BK;           // 64, even

    // Hoisted per-lane staging offsets (element units, 32-bit safe).
    const int gr0 = tid >> 3,         gr1 = (512 + tid) >> 3;
    const int c0  = ((tid & 7) ^ (gr0 & 7)) << 3;
    const int c1  = ((tid & 7) ^ (gr1 & 7)) << 3;
    const int offA0 = ((((gr0 >> 6) << 7) + (gr0 & 63))) * K + c0;
    const int offA1 = ((((gr1 >> 6) << 7) + (gr1 & 63))) * K + c1;
    const int offB0 = ((((gr0 >> 5) << 6) + (gr0 & 31))) * K + c0;
    const int offB1 = ((((gr1 >> 5) << 6) + (gr1 & 31))) * K + c1;
    const int ldsu0 = tid * 8, ldsu1 = (512 + tid) * 8;

#define STAGE_AH0(TK, DST) { gload_lds16(Ag + offA0 + (TK), (DST) + ldsu0); \
                             gload_lds16(Ag + offA1 + (TK), (DST) + ldsu1); }
#define STAGE_AH1(TK, DST) { gload_lds16(Ag + offA0 + 64*K + (TK), (DST) + ldsu0); \
                             gload_lds16(Ag + offA1 + 64*K + (TK), (DST) + ldsu1); }
#define STAGE_BH0(TK, DST) { gload_lds16(Bg + offB0 + (TK), (DST) + ldsu0); \
                             gload_lds16(Bg + offB1 + (TK), (DST) + ldsu1); }
#define STAGE_BH1(TK, DST) { gload_lds16(Bg + offB0 + 32*K + (TK), (DST) + ldsu0); \
                             gload_lds16(Bg + offB1 + 32*K + (TK), (DST) + ldsu1); }

    f32x4 acc[8][4] = {};

    // Prologue: c1 (tile0 P1 regions), c2 (tile0 A-h1), c3 (tile1 P1 regions)
    STAGE_AH0(0,  lds + A_OFS);                          // c1a
    STAGE_BH0(0,  lds + B_OFS);                          // c1b
    STAGE_BH1(0,  lds + B_OFS + REG_HALF);               // c1c
    STAGE_AH1(0,  lds + A_OFS + REG_HALF);               // c2
    STAGE_AH0(BK, lds + BUF_STRIDE + A_OFS);             // c3a
    STAGE_BH0(BK, lds + BUF_STRIDE + B_OFS);             // c3b
    STAGE_BH1(BK, lds + BUF_STRIDE + B_OFS + REG_HALF);  // c3c
    asm volatile("s_waitcnt vmcnt(8)" ::: "memory");     // c1 proven
    SGB();
    BARRIER();                                           // plays BAR((t-1).P2)

#define TILE_ITER(T, CB, NB)                                                   \
    {                                                                          \
        unsigned short* cb_ = (CB);                                            \
        unsigned short* nb_ = (NB);                                            \
        const int tk1 = (((T) + 1 < NT) ? (T) + 1 : NT - 1) * BK;              \
        const int tk2 = (((T) + 2 < NT) ? (T) + 2 : NT - 1) * BK;              \
        bf16x8 afL_[4][2], afH_[4][2], bfA_[2][2], bfB_[2][2];                 \
        /* ---- P1 ---- */                                                     \
        read_af(afL_, cb_ + A_OFS, wm, lr, lk, sx);                            \
        read_bf(bfA_, cb_ + B_OFS, wn, lr, lk, sx);                            \
        read_bf(bfB_, cb_ + B_OFS + REG_HALF, wn, lr, lk, sx);                 \
        asm volatile("s_waitcnt vmcnt(6)" ::: "memory");                       \
        SGB(); BARRIER();                                                      \
        STAGE_AH1(tk1, nb_ + A_OFS + REG_HALF);                                \
        SGB_NOMFMA();                                                          \
        __builtin_amdgcn_s_setprio(1);                                         \
        mfma_quad(acc, 0, 0, afL_, bfA_);                                      \
        mfma_quad(acc, 0, 2, afL_, bfB_);                                      \
        __builtin_amdgcn_s_setprio(0); SGB_NOMFMA();                           \
        /* ---- P2 ---- */                                                     \
        read_af(afH_, cb_ + A_OFS + REG_HALF, wm, lr, lk, sx);                 \
        asm volatile("s_waitcnt vmcnt(2)" ::: "memory");                       \
        SGB(); BARRIER();                                                      \
        STAGE_AH0(tk2, cb_ + A_OFS);                                           \
        STAGE_BH0(tk2, cb_ + B_OFS);                                           \
        STAGE_BH1(tk2, cb_ + B_OFS + REG_HALF);                                \
        SGB_NOMFMA();                                                          \
        __builtin_amdgcn_s_setprio(1);                                         \
        mfma_quad(acc, 4, 0, afH_, bfA_);                                      \
        mfma_quad(acc, 4, 2, afH_, bfB_);                                      \
        __builtin_amdgcn_s_setprio(0); SGB_NOMFMA();                           \
    }

    for (int tt = 0; tt < NT; tt += 2) {
        TILE_ITER(tt,     lds,              lds + BUF_STRIDE);
        TILE_ITER(tt + 1, lds + BUF_STRIDE, lds);
    }
#undef TILE_ITER
#undef STAGE_AH0
#undef STAGE_AH1
#undef STAGE_BH0
#undef STAGE_BH1

    asm volatile("s_waitcnt vmcnt(0) lgkmcnt(0)" ::: "memory"); // drain DMA
    BARRIER();

    // Epilogue (transposed D-fragment): lane&15 = M-row, (lane>>4)*4+j =
    // N-col; acc[mf][nf] = 4 consecutive N-cols at one row -> float4 store.
    const int r0   = bm0 + wm * 128;
    const int cC0  = bn0 + wn * 64;
    const int csub = lk << 2;
#pragma unroll
    for (int nf = 0; nf < 4; ++nf) {
        const int colbase = cC0 + nf * 16 + csub;
        const f32x4 bv = *(const f32x4*)(bias + colbase);
#pragma unroll
        for (int mf = 0; mf < 8; ++mf) {
            const int row = r0 + mf * 16 + lr;
            *(f32x4*)(out + (size_t)row * N + colbase) = acc[mf][nf] + bv;
        }
    }
}

extern "C" void kernel_launch(void* const* d_in, const int* in_sizes, int n_in,
                              void* d_out, int out_size, void* d_ws, size_t ws_size,
                              hipStream_t stream) {
    const float* x = (const float*)d_in[0];   // [M][K] f32
    const float* W = (const float*)d_in[1];   // [N][K] f32
    const float* b = (const float*)d_in[2];   // [N]   f32
    float* out = (float*)d_out;               // [M][N] f32

    const int N = in_sizes[2];                // 4096
    const int K = in_sizes[1] / N;            // 4096
    const int M = in_sizes[0] / K;            // 8192

    unsigned short* xq = (unsigned short*)d_ws;            // 64 MB
    unsigned short* Wb = xq + (size_t)M * K;               // 32 MB

    const int t4x = (int)(((long long)M * K) / 4);
    const int t4w = (int)(((long long)N * K) / 4);
    prep_kernel<<<(t4x + t4w + 255) / 256, 256, 0, stream>>>(x, W, xq, Wb, t4x, t4w);

    dim3 grid((M / 256) * (N / 256));         // 512 blocks
    gemm_kernel<<<grid, 512, 0, stream>>>(xq, Wb, b, out, M, N, K);
}

// Round 19
// 266.658 us; speedup vs baseline: 1.0123x; 1.0123x over previous
//
#include <hip/hip_runtime.h>

using f32x4  = __attribute__((ext_vector_type(4))) float;
using bf16x8 = __attribute__((ext_vector_type(8))) __bf16;
using u16x4  = __attribute__((ext_vector_type(4))) unsigned short;

#define BK 64
#define REG_HALF   8192      // ushorts: 128 rows x 64 cols
#define A_OFS      0
#define B_OFS      16384
#define BUF_STRIDE 32768     // one buffer = A(32KB)+B(32KB) = 64 KB

#define BARRIER() __builtin_amdgcn_s_barrier()
#define SGB()     __builtin_amdgcn_sched_barrier(0)
#define SGB_NOMFMA() __builtin_amdgcn_sched_barrier(0x3F7)

__device__ __forceinline__ unsigned short f32_to_bf16_bits(float f) {
    unsigned int u = __builtin_bit_cast(unsigned int, f);
    u = (u + 0x7fffu + ((u >> 16) & 1u)) >> 16;
    return (unsigned short)u;
}

__device__ __forceinline__ void gload_lds16(const void* g, void* l) {
    __builtin_amdgcn_global_load_lds(
        (const __attribute__((address_space(1))) unsigned int*)g,
        (__attribute__((address_space(3))) unsigned int*)l,
        16, 0, 0);
}

// ---------------------------------------------------------------------------
// Fused prep: fake-quant x (exact-f32 math, bf16 store) + W f32->bf16.
// HBM-bound (~288 MB traffic ≈ its floor).
// ---------------------------------------------------------------------------
__global__ void prep_kernel(const float* __restrict__ x,
                            const float* __restrict__ W,
                            unsigned short* __restrict__ xq,
                            unsigned short* __restrict__ Wb,
                            int t4x, int t4w) {
    int idx = blockIdx.x * 256 + threadIdx.x;
    if (idx < t4x) {
        f32x4 v = *(const f32x4*)(x + (size_t)idx * 4);
        float am = fmaxf(fmaxf(fabsf(v[0]), fabsf(v[1])),
                         fmaxf(fabsf(v[2]), fabsf(v[3])));
        am = fmaxf(am, __shfl_xor(am, 1));
        am = fmaxf(am, __shfl_xor(am, 2));
        am = fmaxf(am, __shfl_xor(am, 4));
        am = fmaxf(am, __shfl_xor(am, 8));
        float delta = fmaxf(am / 127.0f, 1e-5f);
        u16x4 o;
#pragma unroll
        for (int i = 0; i < 4; ++i) {
            float q = rintf(v[i] / delta);           // round-half-even
            q = fminf(fmaxf(q, -127.0f), 127.0f);
            o[i] = f32_to_bf16_bits(q * delta);
        }
        *(u16x4*)(xq + (size_t)idx * 4) = o;
    } else {
        int j = idx - t4x;
        if (j < t4w) {
            f32x4 v = *(const f32x4*)(W + (size_t)j * 4);
            u16x4 o;
#pragma unroll
            for (int i = 0; i < 4; ++i) o[i] = f32_to_bf16_bits(v[i]);
            *(u16x4*)(Wb + (size_t)j * 4) = o;
        }
    }
}

// Fragment readers (region base pointer; T2-swizzled column) ---------------
__device__ __forceinline__ void read_af(bf16x8 (&dst)[4][2],
    const unsigned short* reg, int wm, int lr, int lk, int sx) {
#pragma unroll
    for (int m = 0; m < 4; ++m)
#pragma unroll
        for (int kk = 0; kk < 2; ++kk)
            dst[m][kk] = *(const bf16x8*)(reg
                + (wm * 64 + m * 16 + lr) * 64 + ((((kk << 2) + lk) ^ sx) << 3));
}

__device__ __forceinline__ void read_bf(bf16x8 (&dst)[2][2],
    const unsigned short* reg, int wn, int lr, int lk, int sx) {
#pragma unroll
    for (int n = 0; n < 2; ++n)
#pragma unroll
        for (int kk = 0; kk < 2; ++kk)
            dst[n][kk] = *(const bf16x8*)(reg
                + (wn * 32 + n * 16 + lr) * 64 + ((((kk << 2) + lk) ^ sx) << 3));
}

// Operand-SWAPPED quad: mfma(bf, af) -> D-fragment transposed:
// lane&15 = M-row within m-frag, (lane>>4)*4+j = N-col within n-frag.
// Same products, same f32 accumulation datapath -> numerically identical.
__device__ __forceinline__ void mfma_quad(f32x4 (&acc)[8][4], int mo, int no,
    const bf16x8 (&af)[4][2], const bf16x8 (&bf)[2][2]) {
#pragma unroll
    for (int m = 0; m < 4; ++m)
#pragma unroll
        for (int n = 0; n < 2; ++n)
#pragma unroll
            for (int kk = 0; kk < 2; ++kk)
                acc[mo + m][no + n] = __builtin_amdgcn_mfma_f32_16x16x32_bf16(
                    bf[n][kk], af[m][kk], acc[mo + m][no + n], 0, 0, 0);
}

// ---------------------------------------------------------------------------
// 256x256 bf16 GEMM (B^T). FINAL converged structure (rounds 10-17):
// 4 phases/tile, one vmcnt(6)/tile, rotation bfA pair, stage stream
// P1:A-h1(t+1)->nb, P2:B-h0(t+2)->cb, P3:A-h0(t+2)->cb, P4:B-h1(t+2)->cb.
// Phase = { reads_p ; stage_p ; SGB ; BARRIER ; setprio1 16xMFMA setprio0 ;
//           SGB_NOMFMA }, P4 adds the single vmcnt(6) before its barrier
// and the rotation read + lgkmcnt(0) after it.
// vmcnt(6) counting: leaves exactly {tP2,tP3,tP4} outstanding -> retires
// through t.P1 = everything tile t+1 reads. WAR: every stage follows a
// barrier that follows the dying region's consuming MFMA (lgkm-delivered).
// Operand-swapped MFMA -> transposed D -> epilogue is 32 dwordx4 stores
// per thread (16 rows x 64B contiguous per wave-store), dwordx4 bias loads.
// Register budget: acc 128 AGPR + ~110 VGPR frags — at the 128-VGPR wall;
// deeper rotation/pipelining spills (r5/r9/r11/r16); 2-phase variants lose
// to spill (r9) or read-burst exposure (r18); i8 is VALU-bound for V=64
// rescale (r16). Measured: GEMM ~222us, MfmaUtil ~56%, conflicts 0.
// ---------------------------------------------------------------------------
__global__ __launch_bounds__(512, 2) void gemm_kernel(
    const unsigned short* __restrict__ A,   // [M][K] bf16 bits (quantized x)
    const unsigned short* __restrict__ B,   // [N][K] bf16 bits (W)
    const float* __restrict__ bias,         // [N]
    float* __restrict__ out,                // [M][N] f32
    int M, int N, int K)
{
    __shared__ unsigned short lds[2 * BUF_STRIDE];   // 128 KiB

    const int tid  = threadIdx.x;
    const int lane = tid & 63;
    const int wv   = tid >> 6;
    const int wm   = wv >> 2;        // 0..1  (128 rows each)
    const int wn   = wv & 3;         // 0..3  (64 cols each)
    const int lr   = lane & 15;
    const int lk   = lane >> 4;      // 0..3
    const int sx   = lr & 7;

    const int nbn = N / 256;
    const int nwg = gridDim.x;
    const int cpx = nwg >> 3;        // bijective XCD swizzle (nwg % 8 == 0)
    const int swz = (blockIdx.x & 7) * cpx + (blockIdx.x >> 3);
    const int bm0 = (swz / nbn) * 256;
    const int bn0 = (swz % nbn) * 256;

    const unsigned short* Ag = A + (size_t)bm0 * K;
    const unsigned short* Bg = B + (size_t)bn0 * K;
    const int NT = K / BK;           // 64, even

    // Hoisted per-lane staging offsets (element units, 32-bit safe).
    const int gr0 = tid >> 3,         gr1 = (512 + tid) >> 3;
    const int c0  = ((tid & 7) ^ (gr0 & 7)) << 3;
    const int c1  = ((tid & 7) ^ (gr1 & 7)) << 3;
    const int offA0 = ((((gr0 >> 6) << 7) + (gr0 & 63))) * K + c0;
    const int offA1 = ((((gr1 >> 6) << 7) + (gr1 & 63))) * K + c1;
    const int offB0 = ((((gr0 >> 5) << 6) + (gr0 & 31))) * K + c0;
    const int offB1 = ((((gr1 >> 5) << 6) + (gr1 & 31))) * K + c1;
    const int ldsu0 = tid * 8, ldsu1 = (512 + tid) * 8;

#define STAGE_AH0(TK, DST) { gload_lds16(Ag + offA0 + (TK), (DST) + ldsu0); \
                             gload_lds16(Ag + offA1 + (TK), (DST) + ldsu1); }
#define STAGE_AH1(TK, DST) { gload_lds16(Ag + offA0 + 64*K + (TK), (DST) + ldsu0); \
                             gload_lds16(Ag + offA1 + 64*K + (TK), (DST) + ldsu1); }
#define STAGE_BH0(TK, DST) { gload_lds16(Bg + offB0 + (TK), (DST) + ldsu0); \
                             gload_lds16(Bg + offB1 + (TK), (DST) + ldsu1); }
#define STAGE_BH1(TK, DST) { gload_lds16(Bg + offB0 + 32*K + (TK), (DST) + ldsu0); \
                             gload_lds16(Bg + offB1 + 32*K + (TK), (DST) + ldsu1); }

    f32x4 acc[8][4] = {};

    // Prologue, ledger call order c1..c7 (oldest first):
    STAGE_AH0(0,  lds + A_OFS);                          // c1 A-h0(0)
    STAGE_BH0(0,  lds + B_OFS);                          // c2 B-h0(0)
    STAGE_BH1(0,  lds + B_OFS + REG_HALF);               // c3 B-h1(0)
    STAGE_AH1(0,  lds + A_OFS + REG_HALF);               // c4 A-h1(0)
    STAGE_AH0(BK, lds + BUF_STRIDE + A_OFS);             // c5 A-h0(1)
    STAGE_BH0(BK, lds + BUF_STRIDE + B_OFS);             // c6 B-h0(1)
    STAGE_BH1(BK, lds + BUF_STRIDE + B_OFS + REG_HALF);  // c7 B-h1(1)
    asm volatile("s_waitcnt vmcnt(6)" ::: "memory");     // c1..c4 proven
    SGB();
    BARRIER();

    bf16x8 bfA_e[2][2], bfA_o[2][2];
    read_bf(bfA_e, lds + B_OFS, wn, lr, lk, sx);         // rotation bfA(0)
    asm volatile("s_waitcnt lgkmcnt(0)" ::: "memory");   // delivered
    SGB();
    BARRIER();                                           // plays B((t-1).P4)

#define TILE_ITER(T, CB, NB, BFA_IN, BFA_OUT)                                  \
    {                                                                          \
        unsigned short* cb_ = (CB);                                            \
        unsigned short* nb_ = (NB);                                            \
        const int tk1 = (((T) + 1 < NT) ? (T) + 1 : NT - 1) * BK;              \
        const int tk2 = (((T) + 2 < NT) ? (T) + 2 : NT - 1) * BK;              \
        bf16x8 afL_[4][2], afH_[4][2], bfB_[2][2];                             \
        /* P1: Q1 = afL x bfA_in */                                            \
        read_af(afL_, cb_ + A_OFS, wm, lr, lk, sx);                            \
        STAGE_AH1(tk1, nb_ + A_OFS + REG_HALF);                                \
        SGB(); BARRIER();                                                      \
        __builtin_amdgcn_s_setprio(1);                                         \
        mfma_quad(acc, 0, 0, afL_, BFA_IN);                                    \
        __builtin_amdgcn_s_setprio(0); SGB_NOMFMA();                           \
        /* P2: Q2 = afL x bfB */                                               \
        read_bf(bfB_, cb_ + B_OFS + REG_HALF, wn, lr, lk, sx);                 \
        STAGE_BH0(tk2, cb_ + B_OFS);                                           \
        SGB(); BARRIER();                                                      \
        __builtin_amdgcn_s_setprio(1);                                         \
        mfma_quad(acc, 0, 2, afL_, bfB_);                                      \
        __builtin_amdgcn_s_setprio(0); SGB_NOMFMA();                           \
        /* P3: Q3 = afH x bfA_in */                                            \
        read_af(afH_, cb_ + A_OFS + REG_HALF, wm, lr, lk, sx);                 \
        STAGE_AH0(tk2, cb_ + A_OFS);                                           \
        SGB(); BARRIER();                                                      \
        __builtin_amdgcn_s_setprio(1);                                         \
        mfma_quad(acc, 4, 0, afH_, BFA_IN);                                    \
        __builtin_amdgcn_s_setprio(0); SGB_NOMFMA();                           \
        /* P4: single tile wait; rotation read after its proof barrier */      \
        STAGE_BH1(tk2, cb_ + B_OFS + REG_HALF);                                \
        asm volatile("s_waitcnt vmcnt(6)" ::: "memory");                       \
        SGB(); BARRIER();                                                      \
        read_bf(BFA_OUT, nb_ + B_OFS, wn, lr, lk, sx);                         \
        __builtin_amdgcn_s_setprio(1);                                         \
        mfma_quad(acc, 4, 2, afH_, bfB_);                                      \
        __builtin_amdgcn_s_setprio(0);                                         \
        asm volatile("s_waitcnt lgkmcnt(0)" ::: "memory");                     \
        SGB();                                                                 \
    }

    for (int tt = 0; tt < NT; tt += 2) {
        TILE_ITER(tt,     lds,              lds + BUF_STRIDE, bfA_e, bfA_o);
        TILE_ITER(tt + 1, lds + BUF_STRIDE, lds,              bfA_o, bfA_e);
    }
#undef TILE_ITER
#undef STAGE_AH0
#undef STAGE_AH1
#undef STAGE_BH0
#undef STAGE_BH1

    asm volatile("s_waitcnt vmcnt(0) lgkmcnt(0)" ::: "memory"); // drain DMA
    BARRIER();

    // Epilogue (transposed D-fragment): lane&15 = M-row, (lane>>4)*4+j =
    // N-col. Each acc[mf][nf] is 4 consecutive N-cols at one row ->
    // float4 store. Wave-store = 16 rows x 64 B contiguous.
    const int r0   = bm0 + wm * 128;          // + mf*16 + lr
    const int cC0  = bn0 + wn * 64;           // + nf*16 + (lk<<2)
    const int csub = lk << 2;
#pragma unroll
    for (int nf = 0; nf < 4; ++nf) {
        const int colbase = cC0 + nf * 16 + csub;
        const f32x4 bv = *(const f32x4*)(bias + colbase);
#pragma unroll
        for (int mf = 0; mf < 8; ++mf) {
            const int row = r0 + mf * 16 + lr;
            *(f32x4*)(out + (size_t)row * N + colbase) = acc[mf][nf] + bv;
        }
    }
}

extern "C" void kernel_launch(void* const* d_in, const int* in_sizes, int n_in,
                              void* d_out, int out_size, void* d_ws, size_t ws_size,
                              hipStream_t stream) {
    const float* x = (const float*)d_in[0];   // [M][K] f32
    const float* W = (const float*)d_in[1];   // [N][K] f32
    const float* b = (const float*)d_in[2];   // [N]   f32
    float* out = (float*)d_out;               // [M][N] f32

    const int N = in_sizes[2];                // 4096
    const int K = in_sizes[1] / N;            // 4096
    const int M = in_sizes[0] / K;            // 8192

    unsigned short* xq = (unsigned short*)d_ws;            // 64 MB
    unsigned short* Wb = xq + (size_t)M * K;               // 32 MB

    const int t4x = (int)(((long long)M * K) / 4);
    const int t4w = (int)(((long long)N * K) / 4);
    prep_kernel<<<(t4x + t4w + 255) / 256, 256, 0, stream>>>(x, W, xq, Wb, t4x, t4w);

    dim3 grid((M / 256) * (N / 256));         // 512 blocks
    gemm_kernel<<<grid, 512, 0, stream>>>(xq, Wb, b, out, M, N, K);
}